// Round 12
// baseline (305.650 us; speedup 1.0000x reference)
//
#include <hip/hip_runtime.h>
#include <hip/hip_bf16.h>

#define N_NODES 50000
#define N_EDGES 600000
#define HID 128

typedef __attribute__((ext_vector_type(8))) short s8v;            // 8 bf16 = 4 VGPR
typedef __attribute__((ext_vector_type(8))) unsigned short u8v;   // 8 ushort
typedef __attribute__((ext_vector_type(4))) float f4v;            // MFMA acc

// ---------------- bf16 helpers ----------------
__device__ __forceinline__ unsigned short f2bf(float x) {
    unsigned u = __float_as_uint(x);
    unsigned r = u + 0x7FFFu + ((u >> 16) & 1u);   // RNE
    return (unsigned short)(r >> 16);
}
__device__ __forceinline__ float bf2f(unsigned short u) {
    return __uint_as_float((unsigned)u << 16);
}
__device__ __forceinline__ void split_bf(float x, unsigned short& hi, unsigned short& lo) {
    hi = f2bf(x);
    lo = f2bf(x - bf2f(hi));
}

// ---------------- edge dtype detection (inline, per-wave) ----------------
__device__ __forceinline__ int detect_m64(const void* edges) {
    const int* p = (const int*)edges;
    int lane = threadIdx.x & 63;
    unsigned long long nz = __ballot(p[2 * lane + 1] != 0);
    return (nz == 0ULL) ? 1 : 0;   // 1 => int64
}

__device__ __forceinline__ int edge_at(const void* edges, int mode64, long long idx) {
    return mode64 ? (int)((const long long*)edges)[idx] : ((const int*)edges)[idx];
}

// ---------------- fused prep: count_deg(+rank) + convert_w + split_f32 ----------------
// atomicAdd return value IS the edge's rank in its dst's list -> fill is atomic-free.
__global__ __launch_bounds__(256) void prep(
    const void* __restrict__ edges, const float* __restrict__ x,
    const float* __restrict__ m0, const float* __restrict__ m1,
    const float* __restrict__ m2, const float* __restrict__ m3,
    const float* __restrict__ m4, const float* __restrict__ m5,
    int* __restrict__ deg, int* __restrict__ rank,
    unsigned short* __restrict__ whi, unsigned short* __restrict__ wlo,
    unsigned short* __restrict__ xhi, unsigned short* __restrict__ xlo) {
    const int EB  = (N_EDGES + 255) / 256;          // 2344
    const int WCV = (6 * HID * HID + 255) / 256;    // 384
    const int b = blockIdx.x;
    if (b < EB) {
        int m = detect_m64(edges);
        int e = b * 256 + threadIdx.x;
        if (e >= N_EDGES) return;
        int d = edge_at(edges, m, (long long)N_EDGES + e);
        if ((unsigned)d < (unsigned)N_NODES)
            rank[e] = atomicAdd(&deg[d], 1);
    } else if (b < EB + WCV) {
        int idx = (b - EB) * 256 + threadIdx.x;
        if (idx >= 6 * HID * HID) return;
        int mat = idx >> 14, off = idx & 16383;
        const float* src = mat == 0 ? m0 : mat == 1 ? m1 : mat == 2 ? m2
                         : mat == 3 ? m3 : mat == 4 ? m4 : m5;
        unsigned short h, l;
        split_bf(src[off], h, l);
        whi[idx] = h; wlo[idx] = l;
    } else {
        const int n4 = (N_NODES * HID) / 4;         // 1,600,000
        int i = (b - EB - WCV) * 256 + threadIdx.x;
        if (i >= n4) return;
        float4 v = ((const float4*)x)[i];
        ushort4 h, l;
        split_bf(v.x, h.x, l.x);
        split_bf(v.y, h.y, l.y);
        split_bf(v.z, h.z, l.z);
        split_bf(v.w, h.w, l.w);
        ((ushort4*)xhi)[i] = h;
        ((ushort4*)xlo)[i] = l;
    }
}

// ---------------- CSR scan chain (R5-verified) ----------------
__global__ void scan_block(const int* __restrict__ deg, int* __restrict__ offs,
                           int* __restrict__ blocksum) {
    __shared__ int sm[256];
    int i = blockIdx.x * 256 + threadIdx.x;
    int v = (i < N_NODES) ? deg[i] : 0;
    sm[threadIdx.x] = v;
    __syncthreads();
    #pragma unroll
    for (int s = 1; s < 256; s <<= 1) {
        int t = (threadIdx.x >= (unsigned)s) ? sm[threadIdx.x - s] : 0;
        __syncthreads();
        sm[threadIdx.x] += t;
        __syncthreads();
    }
    if (i < N_NODES) offs[i] = sm[threadIdx.x] - v;
    if (threadIdx.x == 255) blocksum[blockIdx.x] = sm[255];
}

// scan_top merged in: each block reduces blocksum[0..blockIdx) itself (nblocks <= 256).
__global__ void scan_add(int* __restrict__ offs,
                         const int* __restrict__ blocksum, int nblocks) {
    __shared__ int sm[256];
    int t = threadIdx.x;
    int bv = (t < nblocks) ? blocksum[t] : 0;
    sm[t] = (t < (int)blockIdx.x) ? bv : 0;
    __syncthreads();
    #pragma unroll
    for (int s = 128; s > 0; s >>= 1) {
        if (t < s) sm[t] += sm[t + s];
        __syncthreads();
    }
    int prefix = sm[0];
    int i = blockIdx.x * 256 + t;
    if (i < N_NODES) offs[i] += prefix;
    if ((int)blockIdx.x == nblocks - 1 && t == 0)
        offs[N_NODES] = prefix + blocksum[nblocks - 1];
}

// ---------------- CSR fill: atomic-free (rank precomputed in prep) ----------------
__global__ void fill_csr(const void* __restrict__ edges, const int* __restrict__ rank,
                         const int* __restrict__ offs, int* __restrict__ csr) {
    int m = detect_m64(edges);
    int e = blockIdx.x * 256 + threadIdx.x;
    if (e >= N_EDGES) return;
    int d = edge_at(edges, m, (long long)N_EDGES + e);
    int s = edge_at(edges, m, (long long)e);
    if ((unsigned)d >= (unsigned)N_NODES || (unsigned)s >= (unsigned)N_NODES) return;
    csr[offs[d] + rank[e]] = s;
}

// ---------------- mean aggregation: masked 8-batch + 2-deep pipeline ----------------
// (isolated change: batch n+1's 8 gathers issue BEFORE batch n's consume -> 16
// loads in flight per wave. Two named register buffers, static indexing only.
// Batch order + per-batch fma order unchanged -> bit-identical numerics.)
__global__ __launch_bounds__(256) void aggregate_bf16(const unsigned short* __restrict__ h,
                                                      const int* __restrict__ offs,
                                                      const int* __restrict__ csr,
                                                      unsigned short* __restrict__ mhi,
                                                      unsigned short* __restrict__ mlo) {
    const int sub  = threadIdx.x & 15;           // lane within node group
    const int node = blockIdx.x * 16 + (threadIdx.x >> 4);
    if (node >= N_NODES) return;
    const int beg = offs[node], end = offs[node + 1];
    float a[8] = {0.f, 0.f, 0.f, 0.f, 0.f, 0.f, 0.f, 0.f};
    const int e1 = end - 1;

    u8v va[8], vb[8];
    float wa[8], wb[8];
    auto loadB = [&](int p, u8v (&v)[8], float (&w)[8]) {
        int ix[8];
        ix[0] = p;
        #pragma unroll
        for (int k = 1; k < 8; ++k) ix[k] = (p + k < e1) ? p + k : e1;
        #pragma unroll
        for (int k = 0; k < 8; ++k) {
            int s = csr[ix[k]];
            v[k] = *(const u8v*)(h + (size_t)s * HID + sub * 8);
        }
        w[0] = 1.f;
        #pragma unroll
        for (int k = 1; k < 8; ++k) w[k] = (p + k < end) ? 1.f : 0.f;
    };
    auto consume = [&](const u8v (&v)[8], const float (&w)[8]) {
        #pragma unroll
        for (int j = 0; j < 8; ++j) {
            float t = a[j] + bf2f(v[0][j]);
            #pragma unroll
            for (int k = 1; k < 8; ++k) t = fmaf(bf2f(v[k][j]), w[k], t);
            a[j] = t;
        }
    };

    if (beg < end) {
        loadB(beg, va, wa);
        int p = beg;
        while (true) {
            const int pb = p + 8;
            if (pb < end) {
                loadB(pb, vb, wb);     // issue batch n+1 before consuming n
                consume(va, wa);
                const int pa = p + 16;
                if (pa < end) {
                    loadB(pa, va, wa); // issue batch n+2 before consuming n+1
                    consume(vb, wb);
                    p = pa;
                } else {
                    consume(vb, wb);
                    break;
                }
            } else {
                consume(va, wa);
                break;
            }
        }
    }

    const float inv = 1.0f / fmaxf((float)(end - beg), 1.0f);
    u8v hh, ll;
    #pragma unroll
    for (int j = 0; j < 8; ++j) {
        unsigned short hj, lj;
        split_bf(a[j] * inv, hj, lj);
        hh[j] = hj; ll[j] = lj;
    }
    *(u8v*)(mhi + (size_t)node * HID + sub * 8) = hh;
    *(u8v*)(mlo + (size_t)node * HID + sub * 8) = ll;
}

// ---------------- MFMA SAGE GEMM (split-bf16) — R5-exact 128x128 tile ----------------
template <int RELU, int FINAL>
__global__ __launch_bounds__(256) void sage_mfma(
    const unsigned short* __restrict__ Mhi, const unsigned short* __restrict__ Mlo,
    const unsigned short* __restrict__ Hhi, const unsigned short* __restrict__ Hlo,
    const unsigned short* __restrict__ Whi, const unsigned short* __restrict__ Wlo,
    const float* __restrict__ bias,
    unsigned short* __restrict__ ohi, unsigned short* __restrict__ olo,
    float* __restrict__ of32) {
    __shared__ short BhS[128 * 72];   // [col][k-in-panel], stride 72
    __shared__ short BlS[128 * 72];
    const int tid = threadIdx.x;
    const int wave = tid >> 6, lane = tid & 63;
    const int mIdx = lane & 15, q = lane >> 4;
    const int wrow = (wave & 1) * 64, wcol = (wave >> 1) * 64;
    const int rowBase = blockIdx.x * 128;

    size_t aoff[4];
    #pragma unroll
    for (int t = 0; t < 4; ++t) {
        int node = rowBase + wrow + t * 16 + mIdx;
        if (node > N_NODES - 1) node = N_NODES - 1;   // clamp; store is guarded
        aoff[t] = (size_t)node * HID + q * 8;
    }

    const int bcol = tid & 127;
    const int bseg = (tid >> 7) * 32;

    f4v acc[4][4];
    #pragma unroll
    for (int a = 0; a < 4; ++a)
        #pragma unroll
        for (int b = 0; b < 4; ++b) acc[a][b] = (f4v){0.f, 0.f, 0.f, 0.f};

    s8v Ah[2][4], Al[2][4];
    auto loadA = [&](int i, int buf) {         // i = global chunk 0..7
        const unsigned short* ah_ = (i < 4) ? Mhi : Hhi;
        const unsigned short* al_ = (i < 4) ? Mlo : Hlo;
        const int kc = (i & 3) * 32;
        #pragma unroll
        for (int t = 0; t < 4; ++t) {
            Ah[buf][t] = *(const s8v*)(ah_ + aoff[t] + kc);
            Al[buf][t] = *(const s8v*)(al_ + aoff[t] + kc);
        }
    };

    loadA(0, 0);
    for (int panel = 0; panel < 4; ++panel) {  // 64-k panel
        const int ph = panel >> 1;             // 0: Wl, 1: Wr
        const int kb = (panel & 1) * 64;       // k base within phase
        const unsigned short* Wh_ = Whi + ph * HID * HID;
        const unsigned short* Wl_ = Wlo + ph * HID * HID;
        __syncthreads();                        // prev panel's LDS reads done
        {
            const unsigned short* sh = Wh_ + bcol * HID + kb + bseg;
            const unsigned short* sl = Wl_ + bcol * HID + kb + bseg;
            short* dh = BhS + bcol * 72 + bseg;
            short* dl = BlS + bcol * 72 + bseg;
            #pragma unroll
            for (int j = 0; j < 4; ++j) {
                *(s8v*)(dh + j * 8) = *(const s8v*)(sh + j * 8);
                *(s8v*)(dl + j * 8) = *(const s8v*)(sl + j * 8);
            }
        }
        __syncthreads();
        #pragma unroll
        for (int c = 0; c < 2; ++c) {          // two k=32 chunks per panel
            const int i = panel * 2 + c;
            if (i < 7) loadA(i + 1, (i + 1) & 1);
            const int kc2 = c * 32;
            s8v Bh_f[4], Bl_f[4];
            #pragma unroll
            for (int nt = 0; nt < 4; ++nt) {
                const int a = (wcol + nt * 16 + mIdx) * 72 + kc2 + q * 8;
                Bh_f[nt] = *(const s8v*)(BhS + a);
                Bl_f[nt] = *(const s8v*)(BlS + a);
            }
            const int buf = i & 1;
            #pragma unroll
            for (int mt = 0; mt < 4; ++mt)
                #pragma unroll
                for (int nt = 0; nt < 4; ++nt) {
                    acc[mt][nt] = __builtin_amdgcn_mfma_f32_16x16x32_bf16(
                        Ah[buf][mt], Bh_f[nt], acc[mt][nt], 0, 0, 0);
                    acc[mt][nt] = __builtin_amdgcn_mfma_f32_16x16x32_bf16(
                        Al[buf][mt], Bh_f[nt], acc[mt][nt], 0, 0, 0);
                    acc[mt][nt] = __builtin_amdgcn_mfma_f32_16x16x32_bf16(
                        Ah[buf][mt], Bl_f[nt], acc[mt][nt], 0, 0, 0);
                }
        }
    }

    float bv[4];
    #pragma unroll
    for (int nt = 0; nt < 4; ++nt) bv[nt] = bias[wcol + nt * 16 + mIdx];

    #pragma unroll
    for (int mt = 0; mt < 4; ++mt)
        #pragma unroll
        for (int r = 0; r < 4; ++r) {
            int node = rowBase + wrow + mt * 16 + q * 4 + r;
            if (node < N_NODES) {
                #pragma unroll
                for (int nt = 0; nt < 4; ++nt) {
                    int feat = wcol + nt * 16 + mIdx;
                    float v = acc[mt][nt][r] + bv[nt];
                    if (RELU) v = fmaxf(v, 0.f);
                    size_t oidx = (size_t)node * HID + feat;
                    if (FINAL) {
                        of32[oidx] = v;
                    } else {
                        unsigned short hh, ll;
                        split_bf(v, hh, ll);
                        ohi[oidx] = hh;
                        olo[oidx] = ll;
                    }
                }
            }
        }
}

// ---------------- launch ----------------
extern "C" void kernel_launch(void* const* d_in, const int* in_sizes, int n_in,
                              void* d_out, int out_size, void* d_ws, size_t ws_size,
                              hipStream_t stream) {
    const float* x   = (const float*)d_in[0];
    const void* edges = d_in[1];
    const float* Wl1 = (const float*)d_in[2];
    const float* Wr1 = (const float*)d_in[3];
    const float* b1  = (const float*)d_in[4];
    const float* Wl2 = (const float*)d_in[5];
    const float* Wr2 = (const float*)d_in[6];
    const float* b2  = (const float*)d_in[7];
    const float* Wl3 = (const float*)d_in[8];
    const float* Wr3 = (const float*)d_in[9];
    const float* b3  = (const float*)d_in[10];
    float* out = (float*)d_out;

    char* ws = (char*)d_ws;
    size_t off = 0;
    auto alloc = [&](size_t bytes) -> void* {
        void* p = (void*)(ws + off);
        off += (bytes + 255) & ~(size_t)255;
        return p;
    };
    typedef unsigned short u16;
    const size_t FEAT = (size_t)N_NODES * HID;
    int* deg      = (int*)alloc((size_t)N_NODES * 4);
    int* rank     = (int*)alloc((size_t)N_EDGES * 4);
    int* offs     = (int*)alloc((size_t)(N_NODES + 1) * 4);
    int* blocksum = (int*)alloc(256 * 4);
    int* csr      = (int*)alloc((size_t)N_EDGES * 4);
    u16* whi      = (u16*)alloc((size_t)6 * HID * HID * 2);
    u16* wlo      = (u16*)alloc((size_t)6 * HID * HID * 2);
    u16* xhi      = (u16*)alloc(FEAT * 2);   // also reused as h2_hi
    u16* xlo      = (u16*)alloc(FEAT * 2);   // also reused as h2_lo
    u16* h1hi     = (u16*)alloc(FEAT * 2);
    u16* h1lo     = (u16*)alloc(FEAT * 2);
    u16* mhi      = (u16*)alloc(FEAT * 2);
    u16* mlo      = (u16*)alloc(FEAT * 2);
    (void)ws_size; (void)in_sizes; (void)n_in; (void)out_size;

    const int EB    = (N_EDGES + 255) / 256;            // 2344
    const int NB    = (N_NODES + 255) / 256;            // 196  (<= 256 required by scan_add)
    const int WCV   = (6 * HID * HID + 255) / 256;      // 384
    const int XSP   = ((int)(FEAT / 4) + 255) / 256;    // 6250
    const int PREPB = EB + WCV + XSP;                   // 8978
    const int AGG_B = (N_NODES + 15) / 16;              // 3125
    const int GEMM_B = (N_NODES + 127) / 128;           // 391

    hipMemsetAsync(deg, 0, (size_t)N_NODES * 4, stream);
    prep<<<PREPB, 256, 0, stream>>>(edges, x, Wl1, Wr1, Wl2, Wr2, Wl3, Wr3,
                                    deg, rank, whi, wlo, xhi, xlo);
    scan_block<<<NB, 256, 0, stream>>>(deg, offs, blocksum);
    scan_add<<<NB, 256, 0, stream>>>(offs, blocksum, NB);
    fill_csr<<<EB, 256, 0, stream>>>(edges, rank, offs, csr);

    // Layer 1: relu(sage(x)) -> h1 (hi/lo)
    aggregate_bf16<<<AGG_B, 256, 0, stream>>>(xhi, offs, csr, mhi, mlo);
    sage_mfma<1, 0><<<GEMM_B, 256, 0, stream>>>(mhi, mlo, xhi, xlo,
        whi, wlo, b1, h1hi, h1lo, (float*)nullptr);
    // Layer 2 -> h2 (reuses x buffers)
    aggregate_bf16<<<AGG_B, 256, 0, stream>>>(h1hi, offs, csr, mhi, mlo);
    sage_mfma<0, 0><<<GEMM_B, 256, 0, stream>>>(mhi, mlo, h1hi, h1lo,
        whi + 2 * HID * HID, wlo + 2 * HID * HID, b2, xhi, xlo, (float*)nullptr);
    // Layer 3 -> fp32 out
    aggregate_bf16<<<AGG_B, 256, 0, stream>>>(xhi, offs, csr, mhi, mlo);
    sage_mfma<0, 1><<<GEMM_B, 256, 0, stream>>>(mhi, mlo, xhi, xlo,
        whi + 4 * HID * HID, wlo + 4 * HID * HID, b3,
        (u16*)nullptr, (u16*)nullptr, out);
}

// Round 13
// 299.142 us; speedup vs baseline: 1.0218x; 1.0218x over previous
//
#include <hip/hip_runtime.h>
#include <hip/hip_bf16.h>

#define N_NODES 50000
#define N_EDGES 600000
#define HID 128

typedef __attribute__((ext_vector_type(8))) short s8v;            // 8 bf16 = 4 VGPR
typedef __attribute__((ext_vector_type(8))) unsigned short u8v;   // 8 ushort
typedef __attribute__((ext_vector_type(4))) float f4v;            // MFMA acc

// ---------------- bf16 helpers ----------------
__device__ __forceinline__ unsigned short f2bf(float x) {
    unsigned u = __float_as_uint(x);
    unsigned r = u + 0x7FFFu + ((u >> 16) & 1u);   // RNE
    return (unsigned short)(r >> 16);
}
__device__ __forceinline__ float bf2f(unsigned short u) {
    return __uint_as_float((unsigned)u << 16);
}
__device__ __forceinline__ void split_bf(float x, unsigned short& hi, unsigned short& lo) {
    hi = f2bf(x);
    lo = f2bf(x - bf2f(hi));
}

// ---------------- edge dtype detection (inline, per-wave) ----------------
__device__ __forceinline__ int detect_m64(const void* edges) {
    const int* p = (const int*)edges;
    int lane = threadIdx.x & 63;
    unsigned long long nz = __ballot(p[2 * lane + 1] != 0);
    return (nz == 0ULL) ? 1 : 0;   // 1 => int64
}

__device__ __forceinline__ int edge_at(const void* edges, int mode64, long long idx) {
    return mode64 ? (int)((const long long*)edges)[idx] : ((const int*)edges)[idx];
}

// ---------------- fused prep: count_deg(+rank) + convert_w + split_f32 ----------------
// atomicAdd return value IS the edge's rank in its dst's list -> fill is atomic-free.
__global__ __launch_bounds__(256) void prep(
    const void* __restrict__ edges, const float* __restrict__ x,
    const float* __restrict__ m0, const float* __restrict__ m1,
    const float* __restrict__ m2, const float* __restrict__ m3,
    const float* __restrict__ m4, const float* __restrict__ m5,
    int* __restrict__ deg, int* __restrict__ rank,
    unsigned short* __restrict__ whi, unsigned short* __restrict__ wlo,
    unsigned short* __restrict__ xhi, unsigned short* __restrict__ xlo) {
    const int EB  = (N_EDGES + 255) / 256;          // 2344
    const int WCV = (6 * HID * HID + 255) / 256;    // 384
    const int b = blockIdx.x;
    if (b < EB) {
        int m = detect_m64(edges);
        int e = b * 256 + threadIdx.x;
        if (e >= N_EDGES) return;
        int d = edge_at(edges, m, (long long)N_EDGES + e);
        if ((unsigned)d < (unsigned)N_NODES)
            rank[e] = atomicAdd(&deg[d], 1);
    } else if (b < EB + WCV) {
        int idx = (b - EB) * 256 + threadIdx.x;
        if (idx >= 6 * HID * HID) return;
        int mat = idx >> 14, off = idx & 16383;
        const float* src = mat == 0 ? m0 : mat == 1 ? m1 : mat == 2 ? m2
                         : mat == 3 ? m3 : mat == 4 ? m4 : m5;
        unsigned short h, l;
        split_bf(src[off], h, l);
        whi[idx] = h; wlo[idx] = l;
    } else {
        const int n4 = (N_NODES * HID) / 4;         // 1,600,000
        int i = (b - EB - WCV) * 256 + threadIdx.x;
        if (i >= n4) return;
        float4 v = ((const float4*)x)[i];
        ushort4 h, l;
        split_bf(v.x, h.x, l.x);
        split_bf(v.y, h.y, l.y);
        split_bf(v.z, h.z, l.z);
        split_bf(v.w, h.w, l.w);
        ((ushort4*)xhi)[i] = h;
        ((ushort4*)xlo)[i] = l;
    }
}

// ---------------- CSR scan chain (R5-verified) ----------------
__global__ void scan_block(const int* __restrict__ deg, int* __restrict__ offs,
                           int* __restrict__ blocksum) {
    __shared__ int sm[256];
    int i = blockIdx.x * 256 + threadIdx.x;
    int v = (i < N_NODES) ? deg[i] : 0;
    sm[threadIdx.x] = v;
    __syncthreads();
    #pragma unroll
    for (int s = 1; s < 256; s <<= 1) {
        int t = (threadIdx.x >= (unsigned)s) ? sm[threadIdx.x - s] : 0;
        __syncthreads();
        sm[threadIdx.x] += t;
        __syncthreads();
    }
    if (i < N_NODES) offs[i] = sm[threadIdx.x] - v;
    if (threadIdx.x == 255) blocksum[blockIdx.x] = sm[255];
}

// scan_top merged in: each block reduces blocksum[0..blockIdx) itself (nblocks <= 256).
__global__ void scan_add(int* __restrict__ offs,
                         const int* __restrict__ blocksum, int nblocks) {
    __shared__ int sm[256];
    int t = threadIdx.x;
    int bv = (t < nblocks) ? blocksum[t] : 0;
    sm[t] = (t < (int)blockIdx.x) ? bv : 0;
    __syncthreads();
    #pragma unroll
    for (int s = 128; s > 0; s >>= 1) {
        if (t < s) sm[t] += sm[t + s];
        __syncthreads();
    }
    int prefix = sm[0];
    int i = blockIdx.x * 256 + t;
    if (i < N_NODES) offs[i] += prefix;
    if ((int)blockIdx.x == nblocks - 1 && t == 0)
        offs[N_NODES] = prefix + blocksum[nblocks - 1];
}

// ---------------- CSR fill: atomic-free (rank precomputed in prep) ----------------
__global__ void fill_csr(const void* __restrict__ edges, const int* __restrict__ rank,
                         const int* __restrict__ offs, int* __restrict__ csr) {
    int m = detect_m64(edges);
    int e = blockIdx.x * 256 + threadIdx.x;
    if (e >= N_EDGES) return;
    int d = edge_at(edges, m, (long long)N_EDGES + e);
    int s = edge_at(edges, m, (long long)e);
    if ((unsigned)d >= (unsigned)N_NODES || (unsigned)s >= (unsigned)N_NODES) return;
    csr[offs[d] + rank[e]] = s;
}

// ---------------- mean aggregation: masked 8-batch (R9 best-measured version) ----------
// 16 lanes per node, natural node order (coalesced writes). Single masked 8-batch
// loop: clamped indices + 0/1 fma weights -> no serial deg%4 singles tail, and
// all 4 nodes in a wave run ceil(deg/8) uniform iterations (less divergence).
__global__ __launch_bounds__(256) void aggregate_bf16(const unsigned short* __restrict__ h,
                                                      const int* __restrict__ offs,
                                                      const int* __restrict__ csr,
                                                      unsigned short* __restrict__ mhi,
                                                      unsigned short* __restrict__ mlo) {
    const int sub  = threadIdx.x & 15;           // lane within node group
    const int node = blockIdx.x * 16 + (threadIdx.x >> 4);
    if (node >= N_NODES) return;
    const int beg = offs[node], end = offs[node + 1];
    float a[8] = {0.f, 0.f, 0.f, 0.f, 0.f, 0.f, 0.f, 0.f};
    const int e1 = end - 1;
    for (int p = beg; p < end; p += 8) {
        int i1 = p + 1 < e1 ? p + 1 : e1, i2 = p + 2 < e1 ? p + 2 : e1;
        int i3 = p + 3 < e1 ? p + 3 : e1, i4 = p + 4 < e1 ? p + 4 : e1;
        int i5 = p + 5 < e1 ? p + 5 : e1, i6 = p + 6 < e1 ? p + 6 : e1;
        int i7 = p + 7 < e1 ? p + 7 : e1;
        int s0 = csr[p],  s1 = csr[i1], s2 = csr[i2], s3 = csr[i3];
        int s4 = csr[i4], s5 = csr[i5], s6 = csr[i6], s7 = csr[i7];
        u8v v0 = *(const u8v*)(h + (size_t)s0 * HID + sub * 8);
        u8v v1 = *(const u8v*)(h + (size_t)s1 * HID + sub * 8);
        u8v v2 = *(const u8v*)(h + (size_t)s2 * HID + sub * 8);
        u8v v3 = *(const u8v*)(h + (size_t)s3 * HID + sub * 8);
        u8v v4 = *(const u8v*)(h + (size_t)s4 * HID + sub * 8);
        u8v v5 = *(const u8v*)(h + (size_t)s5 * HID + sub * 8);
        u8v v6 = *(const u8v*)(h + (size_t)s6 * HID + sub * 8);
        u8v v7 = *(const u8v*)(h + (size_t)s7 * HID + sub * 8);
        float w1 = (p + 1 < end) ? 1.f : 0.f, w2 = (p + 2 < end) ? 1.f : 0.f;
        float w3 = (p + 3 < end) ? 1.f : 0.f, w4 = (p + 4 < end) ? 1.f : 0.f;
        float w5 = (p + 5 < end) ? 1.f : 0.f, w6 = (p + 6 < end) ? 1.f : 0.f;
        float w7 = (p + 7 < end) ? 1.f : 0.f;
        #pragma unroll
        for (int j = 0; j < 8; ++j) {
            float t = a[j] + bf2f(v0[j]);
            t = fmaf(bf2f(v1[j]), w1, t);
            t = fmaf(bf2f(v2[j]), w2, t);
            t = fmaf(bf2f(v3[j]), w3, t);
            t = fmaf(bf2f(v4[j]), w4, t);
            t = fmaf(bf2f(v5[j]), w5, t);
            t = fmaf(bf2f(v6[j]), w6, t);
            a[j] = fmaf(bf2f(v7[j]), w7, t);
        }
    }
    const float inv = 1.0f / fmaxf((float)(end - beg), 1.0f);
    u8v hh, ll;
    #pragma unroll
    for (int j = 0; j < 8; ++j) {
        unsigned short hj, lj;
        split_bf(a[j] * inv, hj, lj);
        hh[j] = hj; ll[j] = lj;
    }
    *(u8v*)(mhi + (size_t)node * HID + sub * 8) = hh;
    *(u8v*)(mlo + (size_t)node * HID + sub * 8) = ll;
}

// ---------------- MFMA SAGE GEMM (split-bf16) — R5-exact 128x128 tile ----------------
template <int RELU, int FINAL>
__global__ __launch_bounds__(256) void sage_mfma(
    const unsigned short* __restrict__ Mhi, const unsigned short* __restrict__ Mlo,
    const unsigned short* __restrict__ Hhi, const unsigned short* __restrict__ Hlo,
    const unsigned short* __restrict__ Whi, const unsigned short* __restrict__ Wlo,
    const float* __restrict__ bias,
    unsigned short* __restrict__ ohi, unsigned short* __restrict__ olo,
    float* __restrict__ of32) {
    __shared__ short BhS[128 * 72];   // [col][k-in-panel], stride 72
    __shared__ short BlS[128 * 72];
    const int tid = threadIdx.x;
    const int wave = tid >> 6, lane = tid & 63;
    const int mIdx = lane & 15, q = lane >> 4;
    const int wrow = (wave & 1) * 64, wcol = (wave >> 1) * 64;
    const int rowBase = blockIdx.x * 128;

    size_t aoff[4];
    #pragma unroll
    for (int t = 0; t < 4; ++t) {
        int node = rowBase + wrow + t * 16 + mIdx;
        if (node > N_NODES - 1) node = N_NODES - 1;   // clamp; store is guarded
        aoff[t] = (size_t)node * HID + q * 8;
    }

    const int bcol = tid & 127;
    const int bseg = (tid >> 7) * 32;

    f4v acc[4][4];
    #pragma unroll
    for (int a = 0; a < 4; ++a)
        #pragma unroll
        for (int b = 0; b < 4; ++b) acc[a][b] = (f4v){0.f, 0.f, 0.f, 0.f};

    s8v Ah[2][4], Al[2][4];
    auto loadA = [&](int i, int buf) {         // i = global chunk 0..7
        const unsigned short* ah_ = (i < 4) ? Mhi : Hhi;
        const unsigned short* al_ = (i < 4) ? Mlo : Hlo;
        const int kc = (i & 3) * 32;
        #pragma unroll
        for (int t = 0; t < 4; ++t) {
            Ah[buf][t] = *(const s8v*)(ah_ + aoff[t] + kc);
            Al[buf][t] = *(const s8v*)(al_ + aoff[t] + kc);
        }
    };

    loadA(0, 0);
    for (int panel = 0; panel < 4; ++panel) {  // 64-k panel
        const int ph = panel >> 1;             // 0: Wl, 1: Wr
        const int kb = (panel & 1) * 64;       // k base within phase
        const unsigned short* Wh_ = Whi + ph * HID * HID;
        const unsigned short* Wl_ = Wlo + ph * HID * HID;
        __syncthreads();                        // prev panel's LDS reads done
        {
            const unsigned short* sh = Wh_ + bcol * HID + kb + bseg;
            const unsigned short* sl = Wl_ + bcol * HID + kb + bseg;
            short* dh = BhS + bcol * 72 + bseg;
            short* dl = BlS + bcol * 72 + bseg;
            #pragma unroll
            for (int j = 0; j < 4; ++j) {
                *(s8v*)(dh + j * 8) = *(const s8v*)(sh + j * 8);
                *(s8v*)(dl + j * 8) = *(const s8v*)(sl + j * 8);
            }
        }
        __syncthreads();
        #pragma unroll
        for (int c = 0; c < 2; ++c) {          // two k=32 chunks per panel
            const int i = panel * 2 + c;
            if (i < 7) loadA(i + 1, (i + 1) & 1);
            const int kc2 = c * 32;
            s8v Bh_f[4], Bl_f[4];
            #pragma unroll
            for (int nt = 0; nt < 4; ++nt) {
                const int a = (wcol + nt * 16 + mIdx) * 72 + kc2 + q * 8;
                Bh_f[nt] = *(const s8v*)(BhS + a);
                Bl_f[nt] = *(const s8v*)(BlS + a);
            }
            const int buf = i & 1;
            #pragma unroll
            for (int mt = 0; mt < 4; ++mt)
                #pragma unroll
                for (int nt = 0; nt < 4; ++nt) {
                    acc[mt][nt] = __builtin_amdgcn_mfma_f32_16x16x32_bf16(
                        Ah[buf][mt], Bh_f[nt], acc[mt][nt], 0, 0, 0);
                    acc[mt][nt] = __builtin_amdgcn_mfma_f32_16x16x32_bf16(
                        Al[buf][mt], Bh_f[nt], acc[mt][nt], 0, 0, 0);
                    acc[mt][nt] = __builtin_amdgcn_mfma_f32_16x16x32_bf16(
                        Ah[buf][mt], Bl_f[nt], acc[mt][nt], 0, 0, 0);
                }
        }
    }

    float bv[4];
    #pragma unroll
    for (int nt = 0; nt < 4; ++nt) bv[nt] = bias[wcol + nt * 16 + mIdx];

    #pragma unroll
    for (int mt = 0; mt < 4; ++mt)
        #pragma unroll
        for (int r = 0; r < 4; ++r) {
            int node = rowBase + wrow + mt * 16 + q * 4 + r;
            if (node < N_NODES) {
                #pragma unroll
                for (int nt = 0; nt < 4; ++nt) {
                    int feat = wcol + nt * 16 + mIdx;
                    float v = acc[mt][nt][r] + bv[nt];
                    if (RELU) v = fmaxf(v, 0.f);
                    size_t oidx = (size_t)node * HID + feat;
                    if (FINAL) {
                        of32[oidx] = v;
                    } else {
                        unsigned short hh, ll;
                        split_bf(v, hh, ll);
                        ohi[oidx] = hh;
                        olo[oidx] = ll;
                    }
                }
            }
        }
}

// ---------------- launch ----------------
extern "C" void kernel_launch(void* const* d_in, const int* in_sizes, int n_in,
                              void* d_out, int out_size, void* d_ws, size_t ws_size,
                              hipStream_t stream) {
    const float* x   = (const float*)d_in[0];
    const void* edges = d_in[1];
    const float* Wl1 = (const float*)d_in[2];
    const float* Wr1 = (const float*)d_in[3];
    const float* b1  = (const float*)d_in[4];
    const float* Wl2 = (const float*)d_in[5];
    const float* Wr2 = (const float*)d_in[6];
    const float* b2  = (const float*)d_in[7];
    const float* Wl3 = (const float*)d_in[8];
    const float* Wr3 = (const float*)d_in[9];
    const float* b3  = (const float*)d_in[10];
    float* out = (float*)d_out;

    char* ws = (char*)d_ws;
    size_t off = 0;
    auto alloc = [&](size_t bytes) -> void* {
        void* p = (void*)(ws + off);
        off += (bytes + 255) & ~(size_t)255;
        return p;
    };
    typedef unsigned short u16;
    const size_t FEAT = (size_t)N_NODES * HID;
    int* deg      = (int*)alloc((size_t)N_NODES * 4);
    int* rank     = (int*)alloc((size_t)N_EDGES * 4);
    int* offs     = (int*)alloc((size_t)(N_NODES + 1) * 4);
    int* blocksum = (int*)alloc(256 * 4);
    int* csr      = (int*)alloc((size_t)N_EDGES * 4);
    u16* whi      = (u16*)alloc((size_t)6 * HID * HID * 2);
    u16* wlo      = (u16*)alloc((size_t)6 * HID * HID * 2);
    u16* xhi      = (u16*)alloc(FEAT * 2);   // also reused as h2_hi
    u16* xlo      = (u16*)alloc(FEAT * 2);   // also reused as h2_lo
    u16* h1hi     = (u16*)alloc(FEAT * 2);
    u16* h1lo     = (u16*)alloc(FEAT * 2);
    u16* mhi      = (u16*)alloc(FEAT * 2);
    u16* mlo      = (u16*)alloc(FEAT * 2);
    (void)ws_size; (void)in_sizes; (void)n_in; (void)out_size;

    const int EB    = (N_EDGES + 255) / 256;            // 2344
    const int NB    = (N_NODES + 255) / 256;            // 196  (<= 256 required by scan_add)
    const int WCV   = (6 * HID * HID + 255) / 256;      // 384
    const int XSP   = ((int)(FEAT / 4) + 255) / 256;    // 6250
    const int PREPB = EB + WCV + XSP;                   // 8978
    const int AGG_B = (N_NODES + 15) / 16;              // 3125
    const int GEMM_B = (N_NODES + 127) / 128;           // 391

    hipMemsetAsync(deg, 0, (size_t)N_NODES * 4, stream);
    prep<<<PREPB, 256, 0, stream>>>(edges, x, Wl1, Wr1, Wl2, Wr2, Wl3, Wr3,
                                    deg, rank, whi, wlo, xhi, xlo);
    scan_block<<<NB, 256, 0, stream>>>(deg, offs, blocksum);
    scan_add<<<NB, 256, 0, stream>>>(offs, blocksum, NB);
    fill_csr<<<EB, 256, 0, stream>>>(edges, rank, offs, csr);

    // Layer 1: relu(sage(x)) -> h1 (hi/lo)
    aggregate_bf16<<<AGG_B, 256, 0, stream>>>(xhi, offs, csr, mhi, mlo);
    sage_mfma<1, 0><<<GEMM_B, 256, 0, stream>>>(mhi, mlo, xhi, xlo,
        whi, wlo, b1, h1hi, h1lo, (float*)nullptr);
    // Layer 2 -> h2 (reuses x buffers)
    aggregate_bf16<<<AGG_B, 256, 0, stream>>>(h1hi, offs, csr, mhi, mlo);
    sage_mfma<0, 0><<<GEMM_B, 256, 0, stream>>>(mhi, mlo, h1hi, h1lo,
        whi + 2 * HID * HID, wlo + 2 * HID * HID, b2, xhi, xlo, (float*)nullptr);
    // Layer 3 -> fp32 out
    aggregate_bf16<<<AGG_B, 256, 0, stream>>>(xhi, offs, csr, mhi, mlo);
    sage_mfma<0, 1><<<GEMM_B, 256, 0, stream>>>(mhi, mlo, xhi, xlo,
        whi + 4 * HID * HID, wlo + 4 * HID * HID, b3,
        (u16*)nullptr, (u16*)nullptr, out);
}